// Round 1
// baseline (516.227 us; speedup 1.0000x reference)
//
#include <hip/hip_runtime.h>

// KacLayer: out[512][4096] = x @ W^T + b  +  Kac2( vec * Kac1( x ) )
//
// Kernels (all on `stream`, serialized by stream order):
//  1) ksched : per 64-step window, assign each step a dependency "round" such
//     that same-round steps touch pairwise-disjoint columns and program order
//     on shared columns is preserved. Plan (u8 per step) -> d_ws.
//     Reordering commuting Givens rotations is bit-exact.
//  2) kgemm  : bf16-MFMA GEMM (fp32 loads, RNE-convert in staging), writes y+b.
//  3) kwalk  : one wave per row; row in LDS fp32; executes both walks using the
//     precomputed round plan (no barriers, no analysis), then out += row.

#define DIM    4096
#define ROWS   512
#define NSTEPS 49152
#define NWIN   768      // NSTEPS / 64

typedef short  short8 __attribute__((ext_vector_type(8)));
typedef __bf16 bf16x8 __attribute__((ext_vector_type(8)));
typedef float  f32x4  __attribute__((ext_vector_type(4)));

__device__ inline short f2bf(float f) {
    unsigned u = __builtin_bit_cast(unsigned, f);
    u += 0x7FFFu + ((u >> 16) & 1u);          // round-to-nearest-even
    return (short)(u >> 16);
}

__device__ inline short8 pack8(float4 a, float4 b) {
    short8 r;
    r[0] = f2bf(a.x); r[1] = f2bf(a.y); r[2] = f2bf(a.z); r[3] = f2bf(a.w);
    r[4] = f2bf(b.x); r[5] = f2bf(b.y); r[6] = f2bf(b.z); r[7] = f2bf(b.w);
    return r;
}

// ---------------------------------------------------------------------------
// 1) schedule kernel: one wave per 64-step window (1536 windows total)
// ---------------------------------------------------------------------------
__global__ __launch_bounds__(64) void ksched(const int* __restrict__ i1, const int* __restrict__ j1,
                                             const int* __restrict__ i2, const int* __restrict__ j2,
                                             unsigned char* __restrict__ rounds) {
    __shared__ unsigned tbl[DIM];
    const int b    = blockIdx.x;                 // 0 .. 2*NWIN-1
    const int lane = threadIdx.x;
    const int* I   = (b < NWIN) ? i1 : i2;
    const int* J   = (b < NWIN) ? j1 : j2;
    const int widx = (b < NWIN) ? b : b - NWIN;
    const int t    = widx * 64 + lane;
    const int li   = I[t];
    const int lj   = J[t];

    for (int k = lane; k < DIM; k += 64) tbl[k] = 0xFFFFFFFFu;
    __syncthreads();

    unsigned rnd = 0xFFu;
    for (int rr = 0; rr < 64; ++rr) {
        if (!__any(rnd == 0xFFu)) break;
        const bool pending = (rnd == 0xFFu);
        if (pending) {
            atomicMin(&tbl[li], (unsigned)lane);
            atomicMin(&tbl[lj], (unsigned)lane);
        }
        __threadfence_block();
        // winner: min pending lane on BOTH columns -> no earlier pending dep,
        // and two same-round winners can never share a column.
        if (pending && tbl[li] == (unsigned)lane && tbl[lj] == (unsigned)lane)
            rnd = (unsigned)rr;
        __threadfence_block();
        if (pending) { tbl[li] = 0xFFFFFFFFu; tbl[lj] = 0xFFFFFFFFu; }
        __threadfence_block();
    }
    rounds[b * 64 + lane] = (unsigned char)rnd;  // == walk*NSTEPS + t
}

// ---------------------------------------------------------------------------
// 2) bf16 MFMA GEMM: out = x @ W^T + b      (BM=64, BN=128, BK=64, 256 thr)
// ---------------------------------------------------------------------------
#define BM  64
#define BN  128
#define BK  64
#define LDT 72   // padded LDS k-stride (elements): row stride 144B -> 2-way banks (free)

__global__ __launch_bounds__(256) void kgemm(const float* __restrict__ X, const float* __restrict__ W,
                                             const float* __restrict__ bias, float* __restrict__ out) {
    __shared__ short As[BM * LDT];
    __shared__ short Bs[BN * LDT];
    const int tid  = threadIdx.x;
    const int bn   = (blockIdx.x & 31) * BN;   // 32 col tiles
    const int bm   = (blockIdx.x >> 5) * BM;   // 8 row tiles
    const int lane = tid & 63;
    const int wv   = tid >> 6;
    const int wr   = (wv >> 1) * 32;           // wave row quadrant (0/32)
    const int wc   = (wv & 1) * 64;            // wave col quadrant (0/64)
    const int fr   = lane & 15;
    const int ke   = (lane >> 4) * 8;

    f32x4 acc[2][4];
#pragma unroll
    for (int m = 0; m < 2; ++m)
#pragma unroll
        for (int n = 0; n < 4; ++n) acc[m][n] = (f32x4){0.f, 0.f, 0.f, 0.f};

    const int tr = tid >> 2;          // 0..63
    const int tc = (tid & 3) << 4;    // 0,16,32,48

    for (int kt = 0; kt < DIM / BK; ++kt) {
        const int k0 = kt * BK;
        // global -> regs (fp32)
        float4 ra[4], rb[2][4];
        {
            const float4* ga = (const float4*)(X + (size_t)(bm + tr) * DIM + k0 + tc);
#pragma unroll
            for (int q = 0; q < 4; ++q) ra[q] = ga[q];
#pragma unroll
            for (int h = 0; h < 2; ++h) {
                const float4* gb = (const float4*)(W + (size_t)(bn + h * 64 + tr) * DIM + k0 + tc);
#pragma unroll
                for (int q = 0; q < 4; ++q) rb[h][q] = gb[q];
            }
        }
        __syncthreads();   // previous tile's LDS reads done
        // convert + LDS write (bf16)
        *(short8*)&As[tr * LDT + tc]     = pack8(ra[0], ra[1]);
        *(short8*)&As[tr * LDT + tc + 8] = pack8(ra[2], ra[3]);
#pragma unroll
        for (int h = 0; h < 2; ++h) {
            *(short8*)&Bs[(h * 64 + tr) * LDT + tc]     = pack8(rb[h][0], rb[h][1]);
            *(short8*)&Bs[(h * 64 + tr) * LDT + tc + 8] = pack8(rb[h][2], rb[h][3]);
        }
        __syncthreads();
        // fragments + MFMA
#pragma unroll
        for (int kk = 0; kk < BK; kk += 32) {
            short8 af[2], bf[4];
#pragma unroll
            for (int m = 0; m < 2; ++m)
                af[m] = *(const short8*)&As[(wr + m * 16 + fr) * LDT + kk + ke];
#pragma unroll
            for (int n = 0; n < 4; ++n)
                bf[n] = *(const short8*)&Bs[(wc + n * 16 + fr) * LDT + kk + ke];
#pragma unroll
            for (int m = 0; m < 2; ++m)
#pragma unroll
                for (int n = 0; n < 4; ++n)
                    acc[m][n] = __builtin_amdgcn_mfma_f32_16x16x32_bf16(
                        __builtin_bit_cast(bf16x8, af[m]),
                        __builtin_bit_cast(bf16x8, bf[n]),
                        acc[m][n], 0, 0, 0);
        }
    }
    // epilogue: D mapping col=lane&15, row=(lane>>4)*4+reg  [m89-verified]
#pragma unroll
    for (int n = 0; n < 4; ++n) {
        const int col = bn + wc + n * 16 + fr;
        const float bv = bias[col];
#pragma unroll
        for (int m = 0; m < 2; ++m) {
            const int rbase = bm + wr + m * 16 + (lane >> 4) * 4;
#pragma unroll
            for (int r = 0; r < 4; ++r)
                out[(size_t)(rbase + r) * DIM + col] = acc[m][n][r] + bv;
        }
    }
}

// ---------------------------------------------------------------------------
// 3) walk kernel: one wave = one row, row in LDS, plan-driven rounds
// ---------------------------------------------------------------------------
__device__ inline void walk_pass(float* row, const int* __restrict__ I, const int* __restrict__ J,
                                 const float* __restrict__ C, const float* __restrict__ S,
                                 const unsigned char* __restrict__ rds, int lane) {
    int   li = I[lane], lj = J[lane];
    float lc = C[lane], ls = S[lane];
    int   rd = rds[lane];
    for (int w = 0; w < NWIN; ++w) {
        // prefetch next window's params (hides L2 latency under round loop)
        const int nt  = (w < NWIN - 1) ? ((w + 1) * 64 + lane) : (w * 64 + lane);
        const int   nli = I[nt], nlj = J[nt];
        const float nlc = C[nt], nls = S[nt];
        const int   nrd = rds[nt];
        for (int rr = 0; __any(rd >= rr); ++rr) {
            if (rd == rr) {
                const float xi = row[li], xj = row[lj];
                row[li] = lc * xi + ls * xj;
                row[lj] = lc * xj - ls * xi;
            }
        }
        li = nli; lj = nlj; lc = nlc; ls = nls; rd = nrd;
    }
}

__global__ __launch_bounds__(64) void kwalk(const float* __restrict__ X, const float* __restrict__ vec,
    const int* __restrict__ i1, const int* __restrict__ j1, const float* __restrict__ c1, const float* __restrict__ s1,
    const int* __restrict__ i2, const int* __restrict__ j2, const float* __restrict__ c2, const float* __restrict__ s2,
    const unsigned char* __restrict__ rounds, float* __restrict__ out) {
    __shared__ float row[DIM];
    const int r    = blockIdx.x;
    const int lane = threadIdx.x;
    float4* row4 = (float4*)row;

    const float4* x4 = (const float4*)(X + (size_t)r * DIM);
    for (int c = lane; c < DIM / 4; c += 64) row4[c] = x4[c];
    __syncthreads();

    walk_pass(row, i1, j1, c1, s1, rounds, lane);
    __syncthreads();

    const float4* v4 = (const float4*)vec;
    for (int c = lane; c < DIM / 4; c += 64) {
        float4 t0 = row4[c]; const float4 t1 = v4[c];
        t0.x *= t1.x; t0.y *= t1.y; t0.z *= t1.z; t0.w *= t1.w;
        row4[c] = t0;
    }
    __syncthreads();

    walk_pass(row, i2, j2, c2, s2, rounds + NSTEPS, lane);
    __syncthreads();

    float4* o4 = (float4*)(out + (size_t)r * DIM);
    for (int c = lane; c < DIM / 4; c += 64) {
        float4 t0 = o4[c]; const float4 t1 = row4[c];
        t0.x += t1.x; t0.y += t1.y; t0.z += t1.z; t0.w += t1.w;
        o4[c] = t0;
    }
}

// ---------------------------------------------------------------------------
extern "C" void kernel_launch(void* const* d_in, const int* in_sizes, int n_in,
                              void* d_out, int out_size, void* d_ws, size_t ws_size,
                              hipStream_t stream) {
    const float* X    = (const float*)d_in[0];
    const float* W    = (const float*)d_in[1];
    const float* bias = (const float*)d_in[2];
    const float* vec  = (const float*)d_in[3];
    const int*   i1   = (const int*)d_in[4];
    const int*   j1   = (const int*)d_in[5];
    const float* c1   = (const float*)d_in[6];
    const float* s1   = (const float*)d_in[7];
    const int*   i2   = (const int*)d_in[8];
    const int*   j2   = (const int*)d_in[9];
    const float* c2   = (const float*)d_in[10];
    const float* s2   = (const float*)d_in[11];
    float* out = (float*)d_out;
    unsigned char* rounds = (unsigned char*)d_ws;   // 2*NSTEPS = 96 KiB

    hipLaunchKernelGGL(ksched, dim3(2 * NWIN), dim3(64), 0, stream, i1, j1, i2, j2, rounds);
    hipLaunchKernelGGL(kgemm,  dim3(256),      dim3(256), 0, stream, X, W, bias, out);
    hipLaunchKernelGGL(kwalk,  dim3(ROWS),     dim3(64), 0, stream,
                       X, vec, i1, j1, c1, s1, i2, j2, c2, s2, rounds, out);
}